// Round 21
// baseline (26.278 us; speedup 1.0000x reference)
//
#include <hip/hip_runtime.h>

// Tropical (max-times) matmul: out[i,k] = max_j sigmoid(A[j,k]) * x[i,j]
// x: [2048, 256] f32   A: [256, 512] f32   out: [2048, 512] f32
//
// Round 21 = R13's prepack/staging frame + f32 mul/max3 main loop.
// Key finding (R14 counters + R17/R18/R19 nulls): v_pk_*_f16 issues at
// 4 cyc/wave64 on CDNA4 (half the f32 rate) -> packed math gives NO
// throughput gain; main was VALU-saturated at the packed rate (17.3k
// cyc/SIMD). f32 mul + v_max3_f32 is 6 cyc per 2 j vs packed's 8.
//  - x: s_load_dwordx8 DIRECTLY from f32 input (no x-prepack; the
//    prepack dispatch shrinks to W-only, 64 blocks).
//  - W: R13's Wq quad-pair fp16 layout + 32KB LDS slab (0 conflicts,
//    4 blocks/CU), cvt to f32 in-loop (8 cvt/chunk shared over 4 rows).
//  - accuracy: only W is fp16-rounded -> absmax ~5e-3.

typedef _Float16 h1;
typedef __attribute__((ext_vector_type(2))) _Float16 h2v;
typedef __attribute__((ext_vector_type(4))) float f4;
typedef __attribute__((ext_vector_type(8))) float f8;
typedef __attribute__((ext_vector_type(4))) unsigned int u4;

constexpr int JD = 256;
constexpr int KD = 512;

__device__ __forceinline__ float sigmoidf_fast(float a) {
    return 1.0f / (1.0f + __expf(-a));
}

// Wq[p4*512 + k] (u4, 16B): q-th h2v = (sig A[8p4+2q][k], sig A[8p4+2q+1][k])
__global__ __launch_bounds__(256) void prepack_w(const float* __restrict__ A,
                                                 u4* __restrict__ Wq) {
    const int t  = (int)blockIdx.x * 256 + (int)threadIdx.x;   // 0..16383
    const int p4 = t >> 9;                  // 0..31
    const int k  = t & 511;                 // coalesced across lanes
    union { u4 v; h2v h[4]; } u;
    #pragma unroll
    for (int q = 0; q < 4; ++q) {
        const float a0 = A[(8 * p4 + 2 * q) * KD + k];
        const float a1 = A[(8 * p4 + 2 * q + 1) * KD + k];
        u.h[q] = h2v{(h1)sigmoidf_fast(a0), (h1)sigmoidf_fast(a1)};
    }
    Wq[p4 * 512 + k] = u.v;
}

__global__ __launch_bounds__(256) void tropical_main(
        const float* __restrict__ x,
        const u4* __restrict__ Wq,
        float* __restrict__ out) {
    __shared__ u4 Wl[32 * 64];   // [p4][k_local], 16B cells = 32KB

    const int t    = (int)threadIdx.x;
    const int lane = t & 63;
    const int wv   = __builtin_amdgcn_readfirstlane(t >> 6);   // 0..3
    const int kg   = (int)blockIdx.x & 7;      // 8 k-groups of 64
    const int rg   = (int)blockIdx.x >> 3;     // 128 row-groups of 16
    const int k0   = kg * 64;
    const int r0   = rg * 16 + wv * 4;         // this wave's 4 rows

    // ---- stage W slab (verbatim R13; R14-verified 0 bank conflicts) ----
    #pragma unroll
    for (int i = 0; i < 8; ++i) {
        const int p4 = wv * 8 + i;
        Wl[p4 * 64 + lane] = Wq[p4 * 512 + k0 + lane];
    }
    __syncthreads();

    const float* xr = x + r0 * JD;             // uniform base, f32 input

    float acc[4];
    #pragma unroll
    for (int r = 0; r < 4; ++r) acc[r] = -__builtin_inff();

    // ---- main loop: 32 chunks of 8 j; f32 mul + v_max3_f32 ----
    #pragma unroll 4
    for (int c = 0; c < 32; ++c) {
        // x: 4 rows x 32B f32, uniform addresses -> s_load_dwordx8 each
        f8 X[4];
        #pragma unroll
        for (int r = 0; r < 4; ++r)
            X[r] = *(const f8*)(xr + r * JD + c * 8);

        // W: 1 quad-pair cell (8 j), per-lane column, conflict-free b128
        union { u4 v; h2v h[4]; } w;
        w.v = Wl[c * 64 + lane];

        float wf[8];                           // cvt shared across 4 rows
        #pragma unroll
        for (int q = 0; q < 4; ++q) {
            wf[2 * q]     = (float)w.h[q][0];
            wf[2 * q + 1] = (float)w.h[q][1];
        }

        #pragma unroll
        for (int r = 0; r < 4; ++r) {
            #pragma unroll
            for (int q = 0; q < 4; ++q) {
                // fmaxf(fmaxf(p0,p1),acc) -> v_max3_f32
                acc[r] = fmaxf(fmaxf(X[r][2 * q] * wf[2 * q],
                                     X[r][2 * q + 1] * wf[2 * q + 1]),
                               acc[r]);
            }
        }
    }

    // ---- epilogue: coalesced dword stores (f32 acc, no fold) ----
    const int k = k0 + lane;
    #pragma unroll
    for (int r = 0; r < 4; ++r)
        out[(r0 + r) * KD + k] = acc[r];
}

extern "C" void kernel_launch(void* const* d_in, const int* in_sizes, int n_in,
                              void* d_out, int out_size, void* d_ws, size_t ws_size,
                              hipStream_t stream) {
    const float* x = (const float*)d_in[0];
    const float* A = (const float*)d_in[1];
    float* out = (float*)d_out;

    u4* Wq = (u4*)d_ws;                        // 256 KB

    // W-only prepack: 16384 threads
    hipLaunchKernelGGL(prepack_w, dim3(64), dim3(256), 0, stream, A, Wq);

    // 1024 blocks = (128 row-groups) x (8 k-groups); 4 blocks/CU, 16 waves/CU
    hipLaunchKernelGGL(tropical_main, dim3(1024), dim3(256), 0, stream,
                       x, Wq, out);
}